// Round 1
// baseline (236.225 us; speedup 1.0000x reference)
//
#include <hip/hip_runtime.h>
#include <cstdint>

#define B_ 4096
#define D_ 256
#define M_ 60

#define BM 128
#define BN 128
#define BK 32
#define TM 8
#define TN 8
#define PAD 4   // +4 floats keeps ds_read_b128 16B-aligned, breaks 8-way write conflicts to 4-way

typedef unsigned long long u64;

// ---------- prep: row-normalize representations ----------
__global__ void prep_norm_kernel(const float* __restrict__ rep, float* __restrict__ normed) {
    int row = blockIdx.x;
    int t = threadIdx.x;  // 64 threads, one wave
    float4 v = ((const float4*)(rep + (size_t)row * D_))[t];
    float ss = v.x * v.x + v.y * v.y + v.z * v.z + v.w * v.w;
#pragma unroll
    for (int off = 32; off > 0; off >>= 1) ss += __shfl_down(ss, off);
    ss = __shfl(ss, 0);
    float inv = 1.0f / sqrtf(ss);
    float4 o = make_float4(v.x * inv, v.y * inv, v.z * inv, v.w * inv);
    ((float4*)(normed + (size_t)row * D_))[t] = o;
}

// ---------- prep: 128-bit membership masks (VOCAB=100) ----------
__global__ void prep_mask_kernel(const int* __restrict__ codes, u64* __restrict__ lo,
                                 u64* __restrict__ hi, int* __restrict__ cnt) {
    int row = blockIdx.x * blockDim.x + threadIdx.x;
    if (row >= B_) return;
    u64 l = 0, h = 0;
#pragma unroll
    for (int m = 0; m < M_; m++) {
        int c = codes[row * M_ + m];
        if (c < 64) l |= 1ull << c;
        else        h |= 1ull << (c - 64);
    }
    lo[row] = l;
    hi[row] = h;
    cnt[row] = __popcll(l) + __popcll(h);
}

__global__ void init_acc_kernel(double* acc, u64* npos) {
    acc[0] = 0.0; acc[1] = 0.0; acc[2] = 0.0;
    *npos = 0ull;
}

// ---------- fused sim-GEMM + jaccard mask + reductions ----------
__global__ __launch_bounds__(256) void fused_kernel(
    const float* __restrict__ N_,
    const u64* __restrict__ lo, const u64* __restrict__ hi, const int* __restrict__ cnt,
    double* __restrict__ acc, u64* __restrict__ npos) {
    __shared__ float As[BK][BM + PAD];  // k-major
    __shared__ float Bs[BK][BN + PAD];

    const int bi = blockIdx.y;  // row-tile
    const int bj = blockIdx.x;  // col-tile
    const int tid = threadIdx.x;
    const int tx = tid & 15;
    const int ty = tid >> 4;

    const int rowA = bi * BM;
    const int rowB = bj * BN;

    // loader mapping: 256 threads x (4 rows x float4) per tile
    const int lr = tid >> 3;        // base row 0..31
    const int lc = (tid & 7) * 4;   // k-offset 0,4,...,28

    float accr[TM][TN] = {};

    for (int k0 = 0; k0 < D_; k0 += BK) {
        __syncthreads();
#pragma unroll
        for (int rr = 0; rr < 4; rr++) {
            int r = lr + rr * 32;
            float4 va = *(const float4*)(N_ + (size_t)(rowA + r) * D_ + k0 + lc);
            As[lc + 0][r] = va.x; As[lc + 1][r] = va.y;
            As[lc + 2][r] = va.z; As[lc + 3][r] = va.w;
            float4 vb = *(const float4*)(N_ + (size_t)(rowB + r) * D_ + k0 + lc);
            Bs[lc + 0][r] = vb.x; Bs[lc + 1][r] = vb.y;
            Bs[lc + 2][r] = vb.z; Bs[lc + 3][r] = vb.w;
        }
        __syncthreads();
#pragma unroll
        for (int k = 0; k < BK; k++) {
            float a[TM], b[TN];
            *(float4*)&a[0] = *(const float4*)&As[k][ty * TM];
            *(float4*)&a[4] = *(const float4*)&As[k][ty * TM + 4];
            *(float4*)&b[0] = *(const float4*)&Bs[k][tx * TN];
            *(float4*)&b[4] = *(const float4*)&Bs[k][tx * TN + 4];
#pragma unroll
            for (int i = 0; i < TM; i++)
#pragma unroll
                for (int j = 0; j < TN; j++)
                    accr[i][j] += a[i] * b[j];
        }
    }

    // ---------- epilogue: exp, jaccard, partial sums ----------
    const int i0 = rowA + ty * TM;
    const int j0 = rowB + tx * TN;

    u64 blo[TN], bhi[TN];
    int bc[TN];
#pragma unroll
    for (int c = 0; c < TN; c++) {
        blo[c] = lo[j0 + c];
        bhi[c] = hi[j0 + c];
        bc[c] = cnt[j0 + c];
    }

    float t_sum = 0.0f, p_exp = 0.0f, p_s = 0.0f;
    int p_cnt = 0;

#pragma unroll
    for (int r = 0; r < TM; r++) {
        u64 al = lo[i0 + r], ah = hi[i0 + r];
        int ai = cnt[i0 + r];
#pragma unroll
        for (int c = 0; c < TN; c++) {
            float s = accr[r][c] * 10.0f;     // /TEMPERATURE
            float es = __expf(s);
            t_sum += es;
            int inter = __popcll(al & blo[c]) + __popcll(ah & bhi[c]);
            int uni = ai + bc[c] - inter;
            bool pos = (10 * inter > 3 * uni) && ((i0 + r) != (j0 + c));
            if (pos) {
                p_exp += es;
                p_s += s;
                p_cnt++;
            }
        }
    }

    // block reduction in double
    double dt = (double)t_sum, dpe = (double)p_exp, dps = (double)p_s;
    int dc = p_cnt;
#pragma unroll
    for (int off = 32; off > 0; off >>= 1) {
        dt += __shfl_down(dt, off);
        dpe += __shfl_down(dpe, off);
        dps += __shfl_down(dps, off);
        dc += __shfl_down(dc, off);
    }
    __shared__ double redT[4], redPe[4], redPs[4];
    __shared__ int redC[4];
    int wave = tid >> 6, lane = tid & 63;
    if (lane == 0) { redT[wave] = dt; redPe[wave] = dpe; redPs[wave] = dps; redC[wave] = dc; }
    __syncthreads();
    if (tid == 0) {
        double T = 0, Pe = 0, Ps = 0;
        long long C = 0;
        for (int w = 0; w < 4; w++) { T += redT[w]; Pe += redPe[w]; Ps += redPs[w]; C += redC[w]; }
        atomicAdd(&acc[0], T);
        atomicAdd(&acc[1], Pe);
        atomicAdd(&acc[2], Ps);
        atomicAdd(npos, (u64)C);
    }
}

// ---------- finalize ----------
__global__ void finalize_kernel(const double* __restrict__ acc, const u64* __restrict__ npos,
                                float* __restrict__ out) {
    double T = acc[0], Pe = acc[1], Ps = acc[2];
    double n = (double)(*npos);
    double neg = T - Pe;  // sum over negatives (incl. diagonal)
    double loss = 0.0;
    if (n > 0.0) loss = log(neg) + (Pe / neg - Ps) / n;
    out[0] = (float)loss;
}

extern "C" void kernel_launch(void* const* d_in, const int* in_sizes, int n_in,
                              void* d_out, int out_size, void* d_ws, size_t ws_size,
                              hipStream_t stream) {
    const float* rep = (const float*)d_in[0];
    const int* codes = (const int*)d_in[1];
    // d_in[2] = labels, unused by the reference computation

    // workspace layout
    float* normed = (float*)d_ws;                              // 4096*256*4 = 4 MiB
    char* p = (char*)d_ws + (size_t)B_ * D_ * 4;
    u64* lo = (u64*)p;                                         // 32 KiB
    u64* hi = lo + B_;                                         // 32 KiB
    int* cnt = (int*)(hi + B_);                                // 16 KiB
    double* acc = (double*)((char*)(cnt + B_));                // 3 doubles (8B aligned)
    u64* npos = (u64*)(acc + 3);

    float* out = (float*)d_out;

    init_acc_kernel<<<1, 1, 0, stream>>>(acc, npos);
    prep_norm_kernel<<<B_, 64, 0, stream>>>(rep, normed);
    prep_mask_kernel<<<B_ / 256, 256, 0, stream>>>(codes, lo, hi, cnt);
    fused_kernel<<<dim3(B_ / BN, B_ / BM), 256, 0, stream>>>(normed, lo, hi, cnt, acc, npos);
    finalize_kernel<<<1, 1, 0, stream>>>(acc, npos, out);
}

// Round 2
// 99.911 us; speedup vs baseline: 2.3644x; 2.3644x over previous
//
#include <hip/hip_runtime.h>
#include <hip/hip_bf16.h>
#include <cstdint>

#define B_ 4096
#define D_ 256
#define M_ 60
#define NT_ 32          // 128-tiles per dimension
#define BM 128
#define BK 64           // bf16 elements per K-step (128 bytes/row)

typedef unsigned long long u64;
typedef short bf16x8 __attribute__((ext_vector_type(8)));   // 8 bf16 = 4 VGPRs (per guide §3)
typedef float f32x4 __attribute__((ext_vector_type(4)));

__device__ __forceinline__ unsigned short f2bf(float x) {
    __hip_bfloat16 b = __float2bfloat16(x);
    return __builtin_bit_cast(unsigned short, b);
}

// ---------- prep: row-normalize -> bf16, build 128-bit code masks, init accumulators ----------
__global__ void prep_kernel(const float* __restrict__ rep, const int* __restrict__ codes,
                            unsigned short* __restrict__ nb,
                            u64* __restrict__ lo, u64* __restrict__ hi, int* __restrict__ cnt,
                            double* __restrict__ acc, u64* __restrict__ npos) {
    int row = blockIdx.x;
    int t = threadIdx.x;  // 64 threads = 1 wave
    __shared__ u64 sh[2];
    if (t == 0) { sh[0] = 0ull; sh[1] = 0ull; }
    __syncthreads();

    float4 v = ((const float4*)(rep + (size_t)row * D_))[t];
    float ss = v.x * v.x + v.y * v.y + v.z * v.z + v.w * v.w;
#pragma unroll
    for (int off = 32; off > 0; off >>= 1) ss += __shfl_down(ss, off);
    ss = __shfl(ss, 0);
    float inv = 1.0f / sqrtf(ss);
    ushort4 o;
    o.x = f2bf(v.x * inv); o.y = f2bf(v.y * inv);
    o.z = f2bf(v.z * inv); o.w = f2bf(v.w * inv);
    ((ushort4*)(nb + (size_t)row * D_))[t] = o;

    if (t < M_) {
        int c = codes[row * M_ + t];
        if (c < 64) atomicOr(&sh[0], 1ull << c);
        else        atomicOr(&sh[1], 1ull << (c - 64));
    }
    __syncthreads();
    if (t == 0) {
        u64 l = sh[0], h = sh[1];
        lo[row] = l; hi[row] = h;
        cnt[row] = __popcll(l) + __popcll(h);
        if (row == 0) { acc[0] = 0.0; acc[1] = 0.0; acc[2] = 0.0; *npos = 0ull; }
    }
}

// ---------- fused: bf16 MFMA sim-GEMM (upper-triangle tiles) + jaccard + reduction ----------
__global__ __launch_bounds__(256) void fused_kernel(
    const unsigned short* __restrict__ Nb,
    const u64* __restrict__ lo, const u64* __restrict__ hi, const int* __restrict__ cnt,
    double* __restrict__ acc, u64* __restrict__ npos) {
    // 16 KB per operand tile: 128 rows x 64 bf16 (128 B/row), XOR-swizzled 16B chunks
    __shared__ __attribute__((aligned(16))) char smem[2 * BM * BK * 2];
    char* AsB = smem;
    char* BsB = smem + BM * BK * 2;

    const int tid = threadIdx.x;
    const int lane = tid & 63;
    const int w = tid >> 6;
    const int wr = w >> 1, wc = w & 1;
    const int quad = lane >> 4;
    const int l15 = lane & 15;
    const int l7 = lane & 7;

    // block -> (bi, bj) with bj >= bi
    int q = blockIdx.x, bi = 0;
    while (q >= NT_ - bi) { q -= NT_ - bi; bi++; }
    const int bj = bi + q;
    const int rowA = bi * BM, rowB = bj * BM;

    f32x4 accf[4][4] = {};

    for (int k0 = 0; k0 < D_; k0 += BK) {
        __syncthreads();
        // stage A and B tiles via async global->LDS, 16B per lane
        // physical chunk P = region*64 + lane; row = P>>3, pc = P&7, logical chunk c = pc ^ (row&7)
#pragma unroll
        for (int it = 0; it < 4; it++) {
            int region = it * 4 + w;
            int P = region * 64 + lane;
            int row = P >> 3;
            int c = (P & 7) ^ (row & 7);
            const unsigned short* gA = Nb + (size_t)(rowA + row) * D_ + k0 + c * 8;
            const unsigned short* gB = Nb + (size_t)(rowB + row) * D_ + k0 + c * 8;
            __builtin_amdgcn_global_load_lds(
                (const __attribute__((address_space(1))) void*)gA,
                (__attribute__((address_space(3))) void*)(AsB + region * 1024), 16, 0, 0);
            __builtin_amdgcn_global_load_lds(
                (const __attribute__((address_space(1))) void*)gB,
                (__attribute__((address_space(3))) void*)(BsB + region * 1024), 16, 0, 0);
        }
        __syncthreads();
        // compute: 2 mfma-K groups x 16 mfma
#pragma unroll
        for (int kk = 0; kk < 2; kk++) {
            int pc = (kk * 4 + quad) ^ l7;   // swizzled chunk for this lane's fragment
            bf16x8 a[4], b[4];
#pragma unroll
            for (int t = 0; t < 4; t++) {
                int rA = wr * 64 + t * 16 + l15;
                a[t] = *(const bf16x8*)(AsB + rA * 128 + pc * 16);
                int rB = wc * 64 + t * 16 + l15;
                b[t] = *(const bf16x8*)(BsB + rB * 128 + pc * 16);
            }
#pragma unroll
            for (int i = 0; i < 4; i++)
#pragma unroll
                for (int j = 0; j < 4; j++)
                    accf[i][j] = __builtin_amdgcn_mfma_f32_16x16x32_bf16(a[i], b[j], accf[i][j], 0, 0, 0);
        }
    }

    // ---------- epilogue ----------
    // C/D layout (16x16): col = lane&15, row = quad*4 + reg
    int colg[4]; u64 jl[4], jh[4]; int jc[4];
#pragma unroll
    for (int nt = 0; nt < 4; nt++) {
        int cg = rowB + wc * 64 + nt * 16 + l15;
        colg[nt] = cg; jl[nt] = lo[cg]; jh[nt] = hi[cg]; jc[nt] = cnt[cg];
    }

    float t_sum = 0.0f, p_exp = 0.0f, p_s = 0.0f;
    int p_cnt = 0;
#pragma unroll
    for (int mt = 0; mt < 4; mt++) {
        int rbase = rowA + wr * 64 + mt * 16 + quad * 4;
        u64 al[4], ah[4]; int ac[4];
#pragma unroll
        for (int r = 0; r < 4; r++) {
            al[r] = lo[rbase + r]; ah[r] = hi[rbase + r]; ac[r] = cnt[rbase + r];
        }
#pragma unroll
        for (int nt = 0; nt < 4; nt++) {
#pragma unroll
            for (int r = 0; r < 4; r++) {
                float s = accf[mt][nt][r] * 10.0f;   // /TEMPERATURE
                float es = __expf(s);
                t_sum += es;
                int inter = __popcll(al[r] & jl[nt]) + __popcll(ah[r] & jh[nt]);
                int uni = ac[r] + jc[nt] - inter;
                if ((10 * inter > 3 * uni) && (rbase + r != colg[nt])) {
                    p_exp += es; p_s += s; p_cnt++;
                }
            }
        }
    }

    // symmetry weight: off-diagonal tiles count twice
    float scale = (bi == bj) ? 1.0f : 2.0f;
    double dt = (double)t_sum * scale;
    double dpe = (double)p_exp * scale;
    double dps = (double)p_s * scale;
    int dc = p_cnt * ((bi == bj) ? 1 : 2);

#pragma unroll
    for (int off = 32; off > 0; off >>= 1) {
        dt += __shfl_down(dt, off);
        dpe += __shfl_down(dpe, off);
        dps += __shfl_down(dps, off);
        dc += __shfl_down(dc, off);
    }
    __shared__ double redT[4], redPe[4], redPs[4];
    __shared__ int redC[4];
    if (lane == 0) { redT[w] = dt; redPe[w] = dpe; redPs[w] = dps; redC[w] = dc; }
    __syncthreads();
    if (tid == 0) {
        double T = 0, Pe = 0, Ps = 0;
        long long C = 0;
        for (int i = 0; i < 4; i++) { T += redT[i]; Pe += redPe[i]; Ps += redPs[i]; C += redC[i]; }
        atomicAdd(&acc[0], T);
        atomicAdd(&acc[1], Pe);
        atomicAdd(&acc[2], Ps);
        atomicAdd(npos, (u64)C);
    }
}

// ---------- finalize ----------
__global__ void finalize_kernel(const double* __restrict__ acc, const u64* __restrict__ npos,
                                float* __restrict__ out) {
    double T = acc[0], Pe = acc[1], Ps = acc[2];
    double n = (double)(*npos);
    double neg = T - Pe;  // negatives incl. diagonal
    double loss = 0.0;
    if (n > 0.0) loss = log(neg) + (Pe / neg - Ps) / n;
    out[0] = (float)loss;
}

extern "C" void kernel_launch(void* const* d_in, const int* in_sizes, int n_in,
                              void* d_out, int out_size, void* d_ws, size_t ws_size,
                              hipStream_t stream) {
    const float* rep = (const float*)d_in[0];
    const int* codes = (const int*)d_in[1];
    // d_in[2] = labels, unused by the reference computation

    // workspace layout
    unsigned short* nb = (unsigned short*)d_ws;                // 4096*256*2 = 2 MiB
    char* p = (char*)d_ws + (size_t)B_ * D_ * 2;
    u64* lo = (u64*)p;                                         // 32 KiB
    u64* hi = lo + B_;                                         // 32 KiB
    int* cnt = (int*)(hi + B_);                                // 16 KiB
    double* acc = (double*)(cnt + B_);                         // 3 doubles
    u64* npos = (u64*)(acc + 3);

    float* out = (float*)d_out;

    prep_kernel<<<B_, 64, 0, stream>>>(rep, codes, nb, lo, hi, cnt, acc, npos);
    int nblocks = NT_ * (NT_ + 1) / 2;  // 528 upper-triangle tiles
    fused_kernel<<<nblocks, 256, 0, stream>>>(nb, lo, hi, cnt, acc, npos);
    finalize_kernel<<<1, 1, 0, stream>>>(acc, npos, out);
}